// Round 8
// baseline (204.947 us; speedup 1.0000x reference)
//
#include <hip/hip_runtime.h>
#include <cstdint>

#define SEQ   2048
#define BATCH 2
#define EMB   1024
#define NH    16
#define HD    64
#define MROWS (BATCH*SEQ)   // 4096
#define NQKV  (3*EMB)       // 3072
#define SCALE 0.125f
#define L2E   1.4426950408889634f

typedef _Float16 half8 __attribute__((ext_vector_type(8)));
typedef _Float16 half4 __attribute__((ext_vector_type(4)));
typedef __fp16   fp16x2 __attribute__((ext_vector_type(2)));
typedef float    floatx4 __attribute__((ext_vector_type(4)));

#define MFMA(a,b,c) __builtin_amdgcn_mfma_f32_16x16x32_f16(a, b, c, 0, 0, 0)

// async global->LDS, 16B per lane. LDS dest = wave-uniform base + lane*16.
__device__ __forceinline__ void async16(const void* g, const void* l) {
    __builtin_amdgcn_global_load_lds(
        (const __attribute__((address_space(1))) unsigned int*)(uintptr_t)g,
        (__attribute__((address_space(3))) unsigned int*)(uint32_t)(uintptr_t)l,
        16, 0, 0);
}

// ---------------------------------------------------------------- fp32 -> fp16 cast
__global__ void k_split(const float* __restrict__ src, _Float16* __restrict__ hi, int n4) {
    int i = blockIdx.x * blockDim.x + threadIdx.x;
    if (i >= n4) return;
    float4 v = ((const float4*)src)[i];
    half4 h;
    h[0] = (_Float16)v.x;
    h[1] = (_Float16)v.y;
    h[2] = (_Float16)v.z;
    h[3] = (_Float16)v.w;
    ((half4*)hi)[i] = h;
}

// ------------------------------------------- transpose (K,N) fp32 -> (N,K) fp16
__global__ void k_transpose_split(const float* __restrict__ w, _Float16* __restrict__ hi,
                                  int K, int N) {
    __shared__ float t[32][33];
    int n0 = blockIdx.x * 32, k0 = blockIdx.y * 32;
    int tx = threadIdx.x, ty = threadIdx.y;
    #pragma unroll
    for (int i = 0; i < 4; i++)
        t[ty + i * 8][tx] = w[(size_t)(k0 + ty + i * 8) * N + n0 + tx];
    __syncthreads();
    #pragma unroll
    for (int i = 0; i < 4; i++) {
        float v = t[tx][ty + i * 8];           // = w[k0+tx][n0+ty+i*8]
        hi[(size_t)(n0 + ty + i * 8) * K + k0 + tx] = (_Float16)v;
    }
}

// ---------------------------------------------------------------- tiled MFMA GEMM v3
// Wave-specialized producer/consumer: 512 threads = 8 waves. Waves 0-3 consume
// (ds_read+MFMA only -- they never issue vmem, so compiler-inserted
// "s_waitcnt vmcnt(0)" before their ds_reads is dynamically free). Waves 4-7
// produce (async16 + own vmcnt wait). Raw s_barrier pair: [A] tile ready,
// [B] tile consumed. This sidesteps the waitcnt-pass drain that defeats
// in-wave double-buffering (m131/m139 plateau).
// A: (M,K) fp16 row-major. Bt: (N,K) fp16 row-major. Tile 128 x NT.
// MODE 0: qkv epilogue -> scatter Q,K (bh,s,d) and V^T (bh,d,s), fp16.
// MODE 1: plain epilogue -> outC fp32 (M,N) with bias.
template<int MODE, int NT>
__global__ __launch_bounds__(512, 4)
void k_gemm(const _Float16* __restrict__ A, const _Float16* __restrict__ Bt,
            const float* __restrict__ bias,
            _Float16* __restrict__ outQ, _Float16* __restrict__ outK,
            _Float16* __restrict__ outV, float* __restrict__ outC,
            int Mdim, int Ndim, int Kdim) {
    constexpr int WN  = NT / 2;    // wave n-extent
    constexpr int NTI = WN / 16;   // b tiles per consumer wave
    constexpr int LB  = NT / 64;   // B-stage async16 per producer lane per iter
    __shared__ _Float16 As[2][128 * 32];
    __shared__ _Float16 Bs[2][NT * 32];

    const int tid = threadIdx.x;
    const int wid = tid >> 6;
    const int m0 = blockIdx.y * 128, n0 = blockIdx.x * NT;
    const int NIT = Kdim >> 5;

    if (wid >= 4) {
        // ---------------- producer waves ----------------
        const int ptid = tid & 255;
        const int prow = ptid >> 2, pslot = ptid & 3;
        auto stage = [&](int k0, int buf) {
            #pragma unroll
            for (int i = 0; i < 2; i++) {
                int c = i * 256 + ptid;
                int row = i * 64 + prow;
                int q = pslot ^ ((row >> 1) & 3);
                async16(A + (size_t)(m0 + row) * Kdim + k0 + q * 8, As[buf] + c * 8);
            }
            #pragma unroll
            for (int i = 0; i < LB; i++) {
                int c = i * 256 + ptid;
                int row = i * 64 + prow;
                int q = pslot ^ ((row >> 1) & 3);
                async16(Bt + (size_t)(n0 + row) * Kdim + k0 + q * 8, Bs[buf] + c * 8);
            }
        };
        stage(0, 0);                          // preload tile 0
        for (int it = 0; it < NIT; it++) {
            // stage tile it+1 (wraparound keeps vmcnt accounting uniform)
            const int k0n = ((it + 1 == NIT) ? 0 : (it + 1)) << 5;
            stage(k0n, (it & 1) ^ 1);
            // oldest (2+LB) outstanding = tile it's; tile it+1's stay in flight
            if constexpr (LB == 2) asm volatile("s_waitcnt vmcnt(4)" ::: "memory");
            else                   asm volatile("s_waitcnt vmcnt(3)" ::: "memory");
            asm volatile("s_barrier" ::: "memory");   // [A] tile it ready
            asm volatile("s_barrier" ::: "memory");   // [B] tile it consumed
        }
        asm volatile("s_waitcnt vmcnt(0)" ::: "memory");  // drain before endpgm
        return;
    }

    // ---------------- consumer waves ----------------
    const int lane = tid & 63;
    const int quad = lane >> 4, l16 = lane & 15;
    const int wm = (wid >> 1) * 64, wn = (wid & 1) * WN;

    floatx4 acc[4][NTI];
    #pragma unroll
    for (int i = 0; i < 4; i++)
        #pragma unroll
        for (int j = 0; j < NTI; j++)
            acc[i][j] = (floatx4){0.f, 0.f, 0.f, 0.f};

    for (int it = 0; it < NIT; it++) {
        asm volatile("s_barrier" ::: "memory");       // [A] tile it ready
        const int p = it & 1;
        half8 af[4], bf[NTI];
        #pragma unroll
        for (int t = 0; t < 4; t++) {
            int rowA = wm + t * 16 + l16;
            af[t] = *(const half8*)(As[p] + rowA * 32 + (quad ^ ((rowA >> 1) & 3)) * 8);
        }
        #pragma unroll
        for (int t = 0; t < NTI; t++) {
            int rowB = wn + t * 16 + l16;
            bf[t] = *(const half8*)(Bs[p] + rowB * 32 + (quad ^ ((rowB >> 1) & 3)) * 8);
        }
        #pragma unroll
        for (int mt = 0; mt < 4; mt++)
            #pragma unroll
            for (int nt = 0; nt < NTI; nt++)
                acc[mt][nt] = MFMA(af[mt], bf[nt], acc[mt][nt]);
        asm volatile("s_barrier" ::: "memory");       // [B] tile it consumed
    }

    #pragma unroll
    for (int mt = 0; mt < 4; mt++) {
        int rowg = m0 + wm + mt * 16 + quad * 4;
        #pragma unroll
        for (int nt = 0; nt < NTI; nt++) {
            int colg = n0 + wn + nt * 16 + l16;
            float bv = bias[colg];
            if (MODE == 0) {
                int h = colg / 192, rem = colg % 192;
                int d = rem / 3, which = rem % 3;
                #pragma unroll
                for (int r = 0; r < 4; r++) {
                    int m = rowg + r;
                    int b = m >> 11, s = m & (SEQ - 1);
                    int bh = b * NH + h;
                    _Float16 hv = (_Float16)(acc[mt][nt][r] + bv);
                    if (which == 0)      outQ[((size_t)bh * SEQ + s) * HD + d] = hv;
                    else if (which == 1) outK[((size_t)bh * SEQ + s) * HD + d] = hv;
                    else                 outV[((size_t)bh * HD + d) * SEQ + s] = hv;
                }
            } else {
                #pragma unroll
                for (int r = 0; r < 4; r++)
                    outC[(size_t)(rowg + r) * Ndim + colg] = acc[mt][nt][r] + bv;
            }
        }
    }
}

// ---------------------------------------------------------------- flash attention v3
// S^T = K*Q^T with sigma-permuted K rows (S^T acc regs == P A-frags for P*V).
// Double-buffered K/V; softmax denominator accumulated by the MFMA via 16
// all-ones V d-rows. Index domains: sv/mi/al at q=l16; o/o_l at q=quad*4+r.
__device__ __forceinline__ int swzK(int row) { return (row ^ (row >> 2)) & 7; }
__device__ __forceinline__ int swzV(int row) { return (row ^ (row >> 1)) & 7; }

__global__ __launch_bounds__(256, 2)
void k_attn(const _Float16* __restrict__ Q, const _Float16* __restrict__ K,
            const _Float16* __restrict__ Vt, _Float16* __restrict__ Aout) {
    __shared__ __align__(16) _Float16 Ks[2][128 * 64];
    __shared__ __align__(16) _Float16 Vs[2][80 * 128];   // rows 64..79 = ones

    const int tid = threadIdx.x;
    const int lane = tid & 63, wid = tid >> 6;
    const int quad = lane >> 4, l16 = lane & 15;

    // XCD swizzle: all 16 q-blocks of a head on one XCD (n%8 round-robin dispatch)
    const int n = blockIdx.x;
    const int bh = (n & 7) * 4 + (n >> 7);
    const int q0 = ((n >> 3) & 15) * 128;

    const _Float16* Qb = Q  + (size_t)bh * SEQ * HD;
    const _Float16* Kb = K  + (size_t)bh * SEQ * HD;
    const _Float16* Vb = Vt + (size_t)bh * HD * SEQ;

    const int rA = ((l16 >> 2) << 3) | (l16 & 3);     // sigma row base per lane
    const int grayl = (l16 ^ (l16 >> 1)) & 7;

    // ones rows for the l-accumulator tile (both buffers), then one full sync
    {
        half8 one8;
        #pragma unroll
        for (int r = 0; r < 8; r++) one8[r] = (_Float16)1.0f;
        ((half8*)(Vs[0] + 64 * 128))[tid] = one8;
        ((half8*)(Vs[1] + 64 * 128))[tid] = one8;
    }
    __syncthreads();

    // Q fragments (B-operand: n=q=l16, k=quad*8+j), straight from global
    half8 qf[2][2];
    #pragma unroll
    for (int qt = 0; qt < 2; qt++)
        #pragma unroll
        for (int kc = 0; kc < 2; kc++)
            qf[qt][kc] = *(const half8*)(Qb + (size_t)(q0 + wid * 32 + qt * 16 + l16) * HD
                                          + kc * 32 + quad * 8);

    // preload kv tile 0 into buffer 0
    #pragma unroll
    for (int i = 0; i < 4; i++) {
        int c = i * 256 + tid;
        int rowK = c >> 3, posK = c & 7;
        async16(Kb + (size_t)rowK * HD + (posK ^ swzK(rowK)) * 8, Ks[0] + c * 8);
        int rowV = c >> 4, posV = c & 15;
        int qv = (posV & 8) | ((posV & 7) ^ swzV(rowV));
        async16(Vb + (size_t)rowV * SEQ + qv * 8, Vs[0] + c * 8);
    }

    floatx4 o[2][4], o_l[2];
    float mi[2] = {-1e30f, -1e30f};
    #pragma unroll
    for (int qt = 0; qt < 2; qt++) {
        #pragma unroll
        for (int dt = 0; dt < 4; dt++) o[qt][dt] = (floatx4){0.f, 0.f, 0.f, 0.f};
        o_l[qt] = (floatx4){0.f, 0.f, 0.f, 0.f};
    }

    #pragma unroll 2
    for (int t = 0; t < 16; t++) {
        const int p = t & 1;
        // issue next tile (wraparound at t=15 keeps vmcnt accounting exact)
        const int kvn = ((t + 1) & 15) * 128;
        #pragma unroll
        for (int i = 0; i < 4; i++) {
            int c = i * 256 + tid;
            int rowK = c >> 3, posK = c & 7;
            async16(Kb + (size_t)(kvn + rowK) * HD + (posK ^ swzK(rowK)) * 8,
                    Ks[p ^ 1] + c * 8);
            int rowV = c >> 4, posV = c & 15;
            int qv = (posV & 8) | ((posV & 7) ^ swzV(rowV));
            async16(Vb + (size_t)rowV * SEQ + kvn + qv * 8, Vs[p ^ 1] + c * 8);
        }
        // oldest 8 outstanding = this tile's loads; next tile's 8 stay in flight
        asm volatile("s_waitcnt vmcnt(8)" ::: "memory");
        asm volatile("s_barrier" ::: "memory");          // [A] tile p ready

        const _Float16* Ksp = Ks[p];
        const _Float16* Vsp = Vs[p];

        // S^T tiles: sv[u][e][qt] reg r = S^T[kv=32u+8*quad+4e+r][q=l16 (tile qt)]
        floatx4 sv[4][2][2];
        #pragma unroll
        for (int u = 0; u < 4; u++)
            #pragma unroll
            for (int e = 0; e < 2; e++) {
                int row = u * 32 + e * 4 + rA;
                int sw = swzK(row);
                const _Float16* base = Ksp + row * 64;
                half8 kf0 = *(const half8*)(base + ((quad ^ sw) << 3));
                half8 kf1 = *(const half8*)(base + (((quad + 4) ^ sw) << 3));
                floatx4 z = (floatx4){0.f, 0.f, 0.f, 0.f};
                #pragma unroll
                for (int qt = 0; qt < 2; qt++) {
                    floatx4 s = MFMA(kf0, qf[qt][0], z);
                    sv[u][e][qt] = MFMA(kf1, qf[qt][1], s);
                }
            }

        // online max per q-column; rescale o/o_l (q=quad*4+r domain via shuffle)
        #pragma unroll
        for (int qt = 0; qt < 2; qt++) {
            float mb = -1e30f;
            #pragma unroll
            for (int u = 0; u < 4; u++)
                #pragma unroll
                for (int e = 0; e < 2; e++)
                    #pragma unroll
                    for (int r = 0; r < 4; r++)
                        mb = fmaxf(mb, sv[u][e][qt][r]);
            mb = fmaxf(mb, __shfl_xor(mb, 16));
            mb = fmaxf(mb, __shfl_xor(mb, 32));
            float Mn = fmaxf(mi[qt], mb * L2E);          // track in log2 units
            float al = __builtin_amdgcn_exp2f(mi[qt] - Mn);
            mi[qt] = Mn;
            float alq[4];
            #pragma unroll
            for (int r = 0; r < 4; r++)
                alq[r] = __shfl(al, quad * 4 + r);
            #pragma unroll
            for (int dt = 0; dt < 4; dt++)
                #pragma unroll
                for (int r = 0; r < 4; r++)
                    o[qt][dt][r] *= alq[r];
            #pragma unroll
            for (int r = 0; r < 4; r++)
                o_l[qt][r] *= alq[r];
        }

        // exp + pack in-register -> P A-fragments; immediately P*V (+ ones tile)
        #pragma unroll
        for (int u = 0; u < 4; u++) {
            half8 af[2];
            #pragma unroll
            for (int qt = 0; qt < 2; qt++) {
                float p0[8];
                #pragma unroll
                for (int r = 0; r < 4; r++) {
                    p0[r]     = __builtin_amdgcn_exp2f(fmaf(sv[u][0][qt][r], L2E, -mi[qt]));
                    p0[4 + r] = __builtin_amdgcn_exp2f(fmaf(sv[u][1][qt][r], L2E, -mi[qt]));
                }
                union { fp16x2 h2[4]; half8 v; } pk;
                pk.h2[0] = __builtin_amdgcn_cvt_pkrtz(p0[0], p0[1]);
                pk.h2[1] = __builtin_amdgcn_cvt_pkrtz(p0[2], p0[3]);
                pk.h2[2] = __builtin_amdgcn_cvt_pkrtz(p0[4], p0[5]);
                pk.h2[3] = __builtin_amdgcn_cvt_pkrtz(p0[6], p0[7]);
                af[qt] = pk.v;
            }
            int q = u * 4 + quad;
            int slotbase = (q & 8) | ((q & 7) ^ grayl);
            #pragma unroll
            for (int dt = 0; dt < 4; dt++) {
                int row = dt * 16 + l16;
                half8 vf = *(const half8*)(Vsp + row * 128 + slotbase * 8);
                o[0][dt] = MFMA(af[0], vf, o[0][dt]);
                o[1][dt] = MFMA(af[1], vf, o[1][dt]);
            }
            half8 vfl = *(const half8*)(Vsp + (64 + l16) * 128 + slotbase * 8);
            o_l[0] = MFMA(af[0], vfl, o_l[0]);
            o_l[1] = MFMA(af[1], vfl, o_l[1]);
        }

        asm volatile("s_barrier" ::: "memory");          // [B] reads of buf p done
    }

    // epilogue: out = O * SCALE / l   (softmax THEN scale); l = o_l same domain
    int b = bh >> 4, h = bh & 15;
    #pragma unroll
    for (int qt = 0; qt < 2; qt++)
        #pragma unroll
        for (int r = 0; r < 4; r++) {
            float inv = SCALE / o_l[qt][r];
            int srow = q0 + wid * 32 + qt * 16 + quad * 4 + r;
            #pragma unroll
            for (int dt = 0; dt < 4; dt++) {
                int col = h * HD + dt * 16 + l16;
                Aout[(size_t)(b * SEQ + srow) * EMB + col] = (_Float16)(o[qt][dt][r] * inv);
            }
        }
}

// ---------------------------------------------------------------- host
extern "C" void kernel_launch(void* const* d_in, const int* in_sizes, int n_in,
                              void* d_out, int out_size, void* d_ws, size_t ws_size,
                              hipStream_t stream) {
    (void)in_sizes; (void)n_in; (void)out_size; (void)ws_size;
    const float* x      = (const float*)d_in[0];
    const float* w_qkv  = (const float*)d_in[1];
    const float* b_qkv  = (const float*)d_in[2];
    const float* w_proj = (const float*)d_in[3];
    const float* b_proj = (const float*)d_in[4];

    char* ws = (char*)d_ws;
    const size_t MB = 1ull << 20;
    _Float16* x_hi  = (_Float16*)(ws + 0 * MB);    // 8 MB
    _Float16* wq_hi = (_Float16*)(ws + 8 * MB);    // 6 MB (N,K)
    _Float16* wp_hi = (_Float16*)(ws + 14 * MB);   // 2 MB (N,K)
    _Float16* Qb    = (_Float16*)(ws + 16 * MB);   // 8 MB (bh,s,d)
    _Float16* Kb    = (_Float16*)(ws + 24 * MB);   // 8 MB (bh,s,d)
    _Float16* Vtb   = (_Float16*)(ws + 32 * MB);   // 8 MB (bh,d,s)
    _Float16* attb  = (_Float16*)(ws + 40 * MB);   // 8 MB (b*s, emb)

    k_split<<<(MROWS * EMB / 4) / 256, 256, 0, stream>>>(x, x_hi, MROWS * EMB / 4);
    k_transpose_split<<<dim3(NQKV / 32, EMB / 32), dim3(32, 8), 0, stream>>>(
        w_qkv, wq_hi, EMB, NQKV);
    k_transpose_split<<<dim3(EMB / 32, EMB / 32), dim3(32, 8), 0, stream>>>(
        w_proj, wp_hi, EMB, EMB);
    k_gemm<0, 128><<<dim3(NQKV / 128, MROWS / 128), 512, 0, stream>>>(
        x_hi, wq_hi, b_qkv, Qb, Kb, Vtb, nullptr, MROWS, NQKV, EMB);
    k_attn<<<dim3(512), 256, 0, stream>>>(Qb, Kb, Vtb, attb);
    k_gemm<1, 64><<<dim3(EMB / 64, MROWS / 128), 512, 0, stream>>>(
        attb, wp_hi, b_proj, nullptr, nullptr, nullptr,
        (float*)d_out, MROWS, EMB, EMB);
}

// Round 10
// 194.256 us; speedup vs baseline: 1.0550x; 1.0550x over previous
//
#include <hip/hip_runtime.h>
#include <cstdint>

#define SEQ   2048
#define BATCH 2
#define EMB   1024
#define NH    16
#define HD    64
#define MROWS (BATCH*SEQ)   // 4096
#define NQKV  (3*EMB)       // 3072
#define SCALE 0.125f
#define L2E   1.4426950408889634f

typedef _Float16 half8 __attribute__((ext_vector_type(8)));
typedef _Float16 half4 __attribute__((ext_vector_type(4)));
typedef __fp16   fp16x2 __attribute__((ext_vector_type(2)));
typedef float    floatx4 __attribute__((ext_vector_type(4)));

#define MFMA(a,b,c) __builtin_amdgcn_mfma_f32_16x16x32_f16(a, b, c, 0, 0, 0)

// async global->LDS, 16B per lane. LDS dest = wave-uniform base + lane*16.
__device__ __forceinline__ void async16(const void* g, const void* l) {
    __builtin_amdgcn_global_load_lds(
        (const __attribute__((address_space(1))) unsigned int*)(uintptr_t)g,
        (__attribute__((address_space(3))) unsigned int*)(uint32_t)(uintptr_t)l,
        16, 0, 0);
}

// ---------------------------------------------------------------- fp32 -> fp16 cast
__global__ void k_split(const float* __restrict__ src, _Float16* __restrict__ hi, int n4) {
    int i = blockIdx.x * blockDim.x + threadIdx.x;
    if (i >= n4) return;
    float4 v = ((const float4*)src)[i];
    half4 h;
    h[0] = (_Float16)v.x;
    h[1] = (_Float16)v.y;
    h[2] = (_Float16)v.z;
    h[3] = (_Float16)v.w;
    ((half4*)hi)[i] = h;
}

// ------------------------------------------- transpose (K,N) fp32 -> (N,K) fp16
__global__ void k_transpose_split(const float* __restrict__ w, _Float16* __restrict__ hi,
                                  int K, int N) {
    __shared__ float t[32][33];
    int n0 = blockIdx.x * 32, k0 = blockIdx.y * 32;
    int tx = threadIdx.x, ty = threadIdx.y;
    #pragma unroll
    for (int i = 0; i < 4; i++)
        t[ty + i * 8][tx] = w[(size_t)(k0 + ty + i * 8) * N + n0 + tx];
    __syncthreads();
    #pragma unroll
    for (int i = 0; i < 4; i++) {
        float v = t[tx][ty + i * 8];           // = w[k0+tx][n0+ty+i*8]
        hi[(size_t)(n0 + ty + i * 8) * K + k0 + tx] = (_Float16)v;
    }
}

// ---------------------------------------------------------------- tiled MFMA GEMM v4
// Producer/consumer waves + depth-3 LDS pipeline + XCD-locality swizzle.
// 1-D grid; xcd = n&7 (HW round-robins consecutive IDs across the 8 XCDs):
// each XCD owns a 512-row m-band x all n-blocks -> its 1 MB A-band stays L2-
// resident and B tiles are pulled from L3 ~once per XCD (attacks the L3-BW
// wall; latency pipelining alone was neutral in r7/r8).
// Buffer discipline: tile t lives in buf t%3. Producer stages tile it+2 at
// iter it (its buf (it-1)%3 was consumed at barrier B(it-1)); consumer reads
// buf it%3. r9 bug (branchless mod-3 that wasn't) fixed with a rotating index.
// A: (M,K) fp16 row-major. Bt: (N,K) fp16 row-major. Tile 128 x NT.
// MODE 0: qkv epilogue -> scatter Q,K (bh,s,d) and V^T (bh,d,s), fp16.
// MODE 1: plain epilogue -> outC fp32 (M,N) with bias.
template<int MODE, int NT>
__global__ __launch_bounds__(512, 4)
void k_gemm(const _Float16* __restrict__ A, const _Float16* __restrict__ Bt,
            const float* __restrict__ bias,
            _Float16* __restrict__ outQ, _Float16* __restrict__ outK,
            _Float16* __restrict__ outV, float* __restrict__ outC,
            int Mdim, int Ndim, int Kdim) {
    constexpr int WN  = NT / 2;    // wave n-extent
    constexpr int NTI = WN / 16;   // b tiles per consumer wave
    constexpr int LB  = NT / 64;   // B-stage async16 per producer lane per iter
    __shared__ _Float16 As[3][128 * 32];
    __shared__ _Float16 Bs[3][NT * 32];

    const int tid = threadIdx.x;
    const int wid = tid >> 6;
    // XCD swizzle: n&7 = xcd; each xcd gets 4 consecutive y-bands x all x.
    const int n = blockIdx.x;
    const int xcd = n & 7, seq = n >> 3;
    const int by = xcd * 4 + (seq & 3);
    const int bx = seq >> 2;
    const int m0 = by * 128, n0 = bx * NT;
    const int NIT = Kdim >> 5;

    if (wid >= 4) {
        // ---------------- producer waves ----------------
        const int ptid = tid & 255;
        const int prow = ptid >> 2, pslot = ptid & 3;
        auto stage = [&](int k0, int buf) {
            #pragma unroll
            for (int i = 0; i < 2; i++) {
                int c = i * 256 + ptid;
                int row = i * 64 + prow;
                int q = pslot ^ ((row >> 1) & 3);
                async16(A + (size_t)(m0 + row) * Kdim + k0 + q * 8, As[buf] + c * 8);
            }
            #pragma unroll
            for (int i = 0; i < LB; i++) {
                int c = i * 256 + ptid;
                int row = i * 64 + prow;
                int q = pslot ^ ((row >> 1) & 3);
                async16(Bt + (size_t)(n0 + row) * Kdim + k0 + q * 8, Bs[buf] + c * 8);
            }
        };
        stage(0, 0);
        stage(32, 1);
        int b2 = 2;                               // buf for tile it+2 = (it+2)%3
        for (int it = 0; it < NIT; it++) {
            // stage tile it+2 (dummy k0=0 at the tail keeps vmcnt uniform;
            // targets buf (it-1)%3, consumed at barrier B(it-1))
            const int k0n = (it + 2 < NIT) ? ((it + 2) << 5) : 0;
            stage(k0n, b2);
            b2 = (b2 == 2) ? 0 : b2 + 1;
            // outstanding after wait = stages it+1, it+2 -> stage it complete
            if constexpr (LB == 2) asm volatile("s_waitcnt vmcnt(8)" ::: "memory");
            else                   asm volatile("s_waitcnt vmcnt(6)" ::: "memory");
            asm volatile("s_barrier" ::: "memory");   // [A] tile it ready
            asm volatile("s_barrier" ::: "memory");   // [B] tile it consumed
        }
        asm volatile("s_waitcnt vmcnt(0)" ::: "memory");  // drain before endpgm
        return;
    }

    // ---------------- consumer waves (never issue vmem in the loop) ----------------
    const int lane = tid & 63;
    const int quad = lane >> 4, l16 = lane & 15;
    const int wm = (wid >> 1) * 64, wn = (wid & 1) * WN;

    floatx4 acc[4][NTI];
    #pragma unroll
    for (int i = 0; i < 4; i++)
        #pragma unroll
        for (int j = 0; j < NTI; j++)
            acc[i][j] = (floatx4){0.f, 0.f, 0.f, 0.f};

    int p = 0;
    for (int it = 0; it < NIT; it++) {
        asm volatile("s_barrier" ::: "memory");       // [A] tile it ready
        half8 af[4], bf[NTI];
        #pragma unroll
        for (int t = 0; t < 4; t++) {
            int rowA = wm + t * 16 + l16;
            af[t] = *(const half8*)(As[p] + rowA * 32 + (quad ^ ((rowA >> 1) & 3)) * 8);
        }
        #pragma unroll
        for (int t = 0; t < NTI; t++) {
            int rowB = wn + t * 16 + l16;
            bf[t] = *(const half8*)(Bs[p] + rowB * 32 + (quad ^ ((rowB >> 1) & 3)) * 8);
        }
        #pragma unroll
        for (int mt = 0; mt < 4; mt++)
            #pragma unroll
            for (int nt = 0; nt < NTI; nt++)
                acc[mt][nt] = MFMA(af[mt], bf[nt], acc[mt][nt]);
        asm volatile("s_barrier" ::: "memory");       // [B] tile it consumed
        p = (p == 2) ? 0 : p + 1;
    }

    #pragma unroll
    for (int mt = 0; mt < 4; mt++) {
        int rowg = m0 + wm + mt * 16 + quad * 4;
        #pragma unroll
        for (int nt = 0; nt < NTI; nt++) {
            int colg = n0 + wn + nt * 16 + l16;
            float bv = bias[colg];
            if (MODE == 0) {
                int h = colg / 192, rem = colg % 192;
                int d = rem / 3, which = rem % 3;
                #pragma unroll
                for (int r = 0; r < 4; r++) {
                    int m = rowg + r;
                    int b = m >> 11, s = m & (SEQ - 1);
                    int bh = b * NH + h;
                    _Float16 hv = (_Float16)(acc[mt][nt][r] + bv);
                    if (which == 0)      outQ[((size_t)bh * SEQ + s) * HD + d] = hv;
                    else if (which == 1) outK[((size_t)bh * SEQ + s) * HD + d] = hv;
                    else                 outV[((size_t)bh * HD + d) * SEQ + s] = hv;
                }
            } else {
                #pragma unroll
                for (int r = 0; r < 4; r++)
                    outC[(size_t)(rowg + r) * Ndim + colg] = acc[mt][nt][r] + bv;
            }
        }
    }
}

// ---------------------------------------------------------------- flash attention v3
// S^T = K*Q^T with sigma-permuted K rows (S^T acc regs == P A-frags for P*V).
// Double-buffered K/V; softmax denominator accumulated by the MFMA via 16
// all-ones V d-rows. Index domains: sv/mi/al at q=l16; o/o_l at q=quad*4+r.
__device__ __forceinline__ int swzK(int row) { return (row ^ (row >> 2)) & 7; }
__device__ __forceinline__ int swzV(int row) { return (row ^ (row >> 1)) & 7; }

__global__ __launch_bounds__(256, 2)
void k_attn(const _Float16* __restrict__ Q, const _Float16* __restrict__ K,
            const _Float16* __restrict__ Vt, _Float16* __restrict__ Aout) {
    __shared__ __align__(16) _Float16 Ks[2][128 * 64];
    __shared__ __align__(16) _Float16 Vs[2][80 * 128];   // rows 64..79 = ones

    const int tid = threadIdx.x;
    const int lane = tid & 63, wid = tid >> 6;
    const int quad = lane >> 4, l16 = lane & 15;

    // XCD swizzle: all 16 q-blocks of a head on one XCD (n%8 round-robin dispatch)
    const int n = blockIdx.x;
    const int bh = (n & 7) * 4 + (n >> 7);
    const int q0 = ((n >> 3) & 15) * 128;

    const _Float16* Qb = Q  + (size_t)bh * SEQ * HD;
    const _Float16* Kb = K  + (size_t)bh * SEQ * HD;
    const _Float16* Vb = Vt + (size_t)bh * HD * SEQ;

    const int rA = ((l16 >> 2) << 3) | (l16 & 3);     // sigma row base per lane
    const int grayl = (l16 ^ (l16 >> 1)) & 7;

    // ones rows for the l-accumulator tile (both buffers), then one full sync
    {
        half8 one8;
        #pragma unroll
        for (int r = 0; r < 8; r++) one8[r] = (_Float16)1.0f;
        ((half8*)(Vs[0] + 64 * 128))[tid] = one8;
        ((half8*)(Vs[1] + 64 * 128))[tid] = one8;
    }
    __syncthreads();

    // Q fragments (B-operand: n=q=l16, k=quad*8+j), straight from global
    half8 qf[2][2];
    #pragma unroll
    for (int qt = 0; qt < 2; qt++)
        #pragma unroll
        for (int kc = 0; kc < 2; kc++)
            qf[qt][kc] = *(const half8*)(Qb + (size_t)(q0 + wid * 32 + qt * 16 + l16) * HD
                                          + kc * 32 + quad * 8);

    // preload kv tile 0 into buffer 0
    #pragma unroll
    for (int i = 0; i < 4; i++) {
        int c = i * 256 + tid;
        int rowK = c >> 3, posK = c & 7;
        async16(Kb + (size_t)rowK * HD + (posK ^ swzK(rowK)) * 8, Ks[0] + c * 8);
        int rowV = c >> 4, posV = c & 15;
        int qv = (posV & 8) | ((posV & 7) ^ swzV(rowV));
        async16(Vb + (size_t)rowV * SEQ + qv * 8, Vs[0] + c * 8);
    }

    floatx4 o[2][4], o_l[2];
    float mi[2] = {-1e30f, -1e30f};
    #pragma unroll
    for (int qt = 0; qt < 2; qt++) {
        #pragma unroll
        for (int dt = 0; dt < 4; dt++) o[qt][dt] = (floatx4){0.f, 0.f, 0.f, 0.f};
        o_l[qt] = (floatx4){0.f, 0.f, 0.f, 0.f};
    }

    #pragma unroll 2
    for (int t = 0; t < 16; t++) {
        const int p = t & 1;
        // issue next tile (wraparound at t=15 keeps vmcnt accounting exact)
        const int kvn = ((t + 1) & 15) * 128;
        #pragma unroll
        for (int i = 0; i < 4; i++) {
            int c = i * 256 + tid;
            int rowK = c >> 3, posK = c & 7;
            async16(Kb + (size_t)(kvn + rowK) * HD + (posK ^ swzK(rowK)) * 8,
                    Ks[p ^ 1] + c * 8);
            int rowV = c >> 4, posV = c & 15;
            int qv = (posV & 8) | ((posV & 7) ^ swzV(rowV));
            async16(Vb + (size_t)rowV * SEQ + kvn + qv * 8, Vs[p ^ 1] + c * 8);
        }
        // oldest 8 outstanding = this tile's loads; next tile's 8 stay in flight
        asm volatile("s_waitcnt vmcnt(8)" ::: "memory");
        asm volatile("s_barrier" ::: "memory");          // [A] tile p ready

        const _Float16* Ksp = Ks[p];
        const _Float16* Vsp = Vs[p];

        // S^T tiles: sv[u][e][qt] reg r = S^T[kv=32u+8*quad+4e+r][q=l16 (tile qt)]
        floatx4 sv[4][2][2];
        #pragma unroll
        for (int u = 0; u < 4; u++)
            #pragma unroll
            for (int e = 0; e < 2; e++) {
                int row = u * 32 + e * 4 + rA;
                int sw = swzK(row);
                const _Float16* base = Ksp + row * 64;
                half8 kf0 = *(const half8*)(base + ((quad ^ sw) << 3));
                half8 kf1 = *(const half8*)(base + (((quad + 4) ^ sw) << 3));
                floatx4 z = (floatx4){0.f, 0.f, 0.f, 0.f};
                #pragma unroll
                for (int qt = 0; qt < 2; qt++) {
                    floatx4 s = MFMA(kf0, qf[qt][0], z);
                    sv[u][e][qt] = MFMA(kf1, qf[qt][1], s);
                }
            }

        // online max per q-column; rescale o/o_l (q=quad*4+r domain via shuffle)
        #pragma unroll
        for (int qt = 0; qt < 2; qt++) {
            float mb = -1e30f;
            #pragma unroll
            for (int u = 0; u < 4; u++)
                #pragma unroll
                for (int e = 0; e < 2; e++)
                    #pragma unroll
                    for (int r = 0; r < 4; r++)
                        mb = fmaxf(mb, sv[u][e][qt][r]);
            mb = fmaxf(mb, __shfl_xor(mb, 16));
            mb = fmaxf(mb, __shfl_xor(mb, 32));
            float Mn = fmaxf(mi[qt], mb * L2E);          // track in log2 units
            float al = __builtin_amdgcn_exp2f(mi[qt] - Mn);
            mi[qt] = Mn;
            float alq[4];
            #pragma unroll
            for (int r = 0; r < 4; r++)
                alq[r] = __shfl(al, quad * 4 + r);
            #pragma unroll
            for (int dt = 0; dt < 4; dt++)
                #pragma unroll
                for (int r = 0; r < 4; r++)
                    o[qt][dt][r] *= alq[r];
            #pragma unroll
            for (int r = 0; r < 4; r++)
                o_l[qt][r] *= alq[r];
        }

        // exp + pack in-register -> P A-fragments; immediately P*V (+ ones tile)
        #pragma unroll
        for (int u = 0; u < 4; u++) {
            half8 af[2];
            #pragma unroll
            for (int qt = 0; qt < 2; qt++) {
                float p0[8];
                #pragma unroll
                for (int r = 0; r < 4; r++) {
                    p0[r]     = __builtin_amdgcn_exp2f(fmaf(sv[u][0][qt][r], L2E, -mi[qt]));
                    p0[4 + r] = __builtin_amdgcn_exp2f(fmaf(sv[u][1][qt][r], L2E, -mi[qt]));
                }
                union { fp16x2 h2[4]; half8 v; } pk;
                pk.h2[0] = __builtin_amdgcn_cvt_pkrtz(p0[0], p0[1]);
                pk.h2[1] = __builtin_amdgcn_cvt_pkrtz(p0[2], p0[3]);
                pk.h2[2] = __builtin_amdgcn_cvt_pkrtz(p0[4], p0[5]);
                pk.h2[3] = __builtin_amdgcn_cvt_pkrtz(p0[6], p0[7]);
                af[qt] = pk.v;
            }
            int q = u * 4 + quad;
            int slotbase = (q & 8) | ((q & 7) ^ grayl);
            #pragma unroll
            for (int dt = 0; dt < 4; dt++) {
                int row = dt * 16 + l16;
                half8 vf = *(const half8*)(Vsp + row * 128 + slotbase * 8);
                o[0][dt] = MFMA(af[0], vf, o[0][dt]);
                o[1][dt] = MFMA(af[1], vf, o[1][dt]);
            }
            half8 vfl = *(const half8*)(Vsp + (64 + l16) * 128 + slotbase * 8);
            o_l[0] = MFMA(af[0], vfl, o_l[0]);
            o_l[1] = MFMA(af[1], vfl, o_l[1]);
        }

        asm volatile("s_barrier" ::: "memory");          // [B] reads of buf p done
    }

    // epilogue: out = O * SCALE / l   (softmax THEN scale); l = o_l same domain
    int b = bh >> 4, h = bh & 15;
    #pragma unroll
    for (int qt = 0; qt < 2; qt++)
        #pragma unroll
        for (int r = 0; r < 4; r++) {
            float inv = SCALE / o_l[qt][r];
            int srow = q0 + wid * 32 + qt * 16 + quad * 4 + r;
            #pragma unroll
            for (int dt = 0; dt < 4; dt++) {
                int col = h * HD + dt * 16 + l16;
                Aout[(size_t)(b * SEQ + srow) * EMB + col] = (_Float16)(o[qt][dt][r] * inv);
            }
        }
}

// ---------------------------------------------------------------- host
extern "C" void kernel_launch(void* const* d_in, const int* in_sizes, int n_in,
                              void* d_out, int out_size, void* d_ws, size_t ws_size,
                              hipStream_t stream) {
    (void)in_sizes; (void)n_in; (void)out_size; (void)ws_size;
    const float* x      = (const float*)d_in[0];
    const float* w_qkv  = (const float*)d_in[1];
    const float* b_qkv  = (const float*)d_in[2];
    const float* w_proj = (const float*)d_in[3];
    const float* b_proj = (const float*)d_in[4];

    char* ws = (char*)d_ws;
    const size_t MB = 1ull << 20;
    _Float16* x_hi  = (_Float16*)(ws + 0 * MB);    // 8 MB
    _Float16* wq_hi = (_Float16*)(ws + 8 * MB);    // 6 MB (N,K)
    _Float16* wp_hi = (_Float16*)(ws + 14 * MB);   // 2 MB (N,K)
    _Float16* Qb    = (_Float16*)(ws + 16 * MB);   // 8 MB (bh,s,d)
    _Float16* Kb    = (_Float16*)(ws + 24 * MB);   // 8 MB (bh,s,d)
    _Float16* Vtb   = (_Float16*)(ws + 32 * MB);   // 8 MB (bh,d,s)
    _Float16* attb  = (_Float16*)(ws + 40 * MB);   // 8 MB (b*s, emb)

    k_split<<<(MROWS * EMB / 4) / 256, 256, 0, stream>>>(x, x_hi, MROWS * EMB / 4);
    k_transpose_split<<<dim3(NQKV / 32, EMB / 32), dim3(32, 8), 0, stream>>>(
        w_qkv, wq_hi, EMB, NQKV);
    k_transpose_split<<<dim3(EMB / 32, EMB / 32), dim3(32, 8), 0, stream>>>(
        w_proj, wp_hi, EMB, EMB);
    // 1-D grids: 768 = 8 xcd * (4 y * 24 x); 512 = 8 xcd * (4 y * 16 x)
    k_gemm<0, 128><<<dim3(768), 512, 0, stream>>>(
        x_hi, wq_hi, b_qkv, Qb, Kb, Vtb, nullptr, MROWS, NQKV, EMB);
    k_attn<<<dim3(512), 256, 0, stream>>>(Qb, Kb, Vtb, attb);
    k_gemm<1, 64><<<dim3(512), 512, 0, stream>>>(
        attb, wp_hi, b_proj, nullptr, nullptr, nullptr,
        (float*)d_out, MROWS, EMB, EMB);
}